// Round 3
// baseline (365.323 us; speedup 1.0000x reference)
//
#include <hip/hip_runtime.h>
#include <hip/hip_bf16.h>

// Fused Linear([16,8192,256] x [256,256]^T) + per-batch BatchNorm over N=8192.
// bf16x3 split-GEMM (hi*hi + hi*lo + lo*hi) => fp32-class accuracy on MFMA.
// Bias b dropped: BN mean-subtraction cancels any per-feature constant exactly.
//
// R2: fix ushort4 typedef collision with HIP's built-in vector types
// (renamed to us4/us8). Logic identical to R1:
//  - W pre-split once into bf16 hi/lo (ws), B fragments read direct from
//    global/L2 (each lg-quad consumes a full 64B line) -> LDS = A only, 32KB.
//  - wave tile 64x32 (BM=128,BN=64, 4 waves) -> 4 blocks/CU, 16 waves/CU.
//  - stats written transposed [o][rblk]; reduce = 1 wave per (b,o), coalesced.

typedef __attribute__((ext_vector_type(8))) __bf16 bf16x8;
typedef __attribute__((ext_vector_type(4))) float f32x4;
typedef __attribute__((ext_vector_type(8))) unsigned short us8;
typedef __attribute__((ext_vector_type(4))) unsigned short us4;

#define BDIM   16
#define NDIM   8192
#define FIN    256
#define FOUT   256
#define BM     128
#define BN     64
#define BK     64
#define NTHREADS 256
#define NRBLK  (BDIM * NDIM / BM)   // 1024 row blocks
#define NCBLK  (FOUT / BN)          // 4 col blocks

__device__ __forceinline__ void split8(const float4 v0, const float4 v1,
                                       us8& h, us8& l) {
  float f[8] = {v0.x, v0.y, v0.z, v0.w, v1.x, v1.y, v1.z, v1.w};
#pragma unroll
  for (int i = 0; i < 8; ++i) {
    unsigned int u = __float_as_uint(f[i]);
    h[i] = (unsigned short)(u >> 16);
    float rem = f[i] - __uint_as_float(u & 0xFFFF0000u);
    l[i] = (unsigned short)(__float_as_uint(rem) >> 16);
  }
}

// K0: split W (fp32 [col][k]) -> bf16 hi/lo, same row-major layout.
__global__ void split_w(const float4* __restrict__ Wv,
                        us4* __restrict__ Wh, us4* __restrict__ Wl) {
  int gid = blockIdx.x * blockDim.x + threadIdx.x;  // 0..16383
  float4 v = Wv[gid];
  float f[4] = {v.x, v.y, v.z, v.w};
  us4 h, l;
#pragma unroll
  for (int i = 0; i < 4; ++i) {
    unsigned int u = __float_as_uint(f[i]);
    h[i] = (unsigned short)(u >> 16);
    float rem = f[i] - __uint_as_float(u & 0xFFFF0000u);
    l[i] = (unsigned short)(__float_as_uint(rem) >> 16);
  }
  Wh[gid] = h;
  Wl[gid] = l;
}

// MODE 0: write y to Y + transposed partial stats.  MODE 1: stats only.
// MODE 2: apply per-(b,o) scale/shift, write normalized out.
template <int MODE>
__global__ __launch_bounds__(NTHREADS, 4)
void fused_gemm(const float* __restrict__ X,
                const unsigned short* __restrict__ Wh,
                const unsigned short* __restrict__ Wl,
                float* __restrict__ Y,
                float* __restrict__ P1, float* __restrict__ P2,
                const float* __restrict__ Sc, const float* __restrict__ Tc) {
  __shared__ __align__(16) char lds[2 * BM * BK * 2];  // A hi 16K + A lo 16K
  char* Abh = lds;
  char* Abl = lds + BM * BK * 2;

  const int tid  = threadIdx.x;
  const int rblk = blockIdx.x;            // 0..1023
  const int cblk = blockIdx.y;            // 0..3
  const size_t rowBase = (size_t)rblk * BM;
  const int colBase = cblk * BN;

  const int wid = tid >> 6, lane = tid & 63;
  const int wr = wid >> 1, wc = wid & 1;  // 2x2 waves; wave tile 64x32
  const int lg = lane >> 4, lr = lane & 15;

  f32x4 acc[4][2];
#pragma unroll
  for (int m = 0; m < 4; ++m)
#pragma unroll
    for (int n = 0; n < 2; ++n) acc[m][n] = f32x4{0.f, 0.f, 0.f, 0.f};

  for (int ks = 0; ks < FIN / BK; ++ks) {
    const int k0 = ks * BK;
    // ---- stage A: 128 rows x 64 k fp32 -> bf16 hi/lo, XOR-swizzled ----
#pragma unroll
    for (int c = 0; c < 4; ++c) {
      int id = tid + c * NTHREADS;        // 0..1023
      int r  = id >> 3;                   // row 0..127
      int kc = id & 7;                    // 8-float chunk
      const float4* ga =
          (const float4*)(X + (rowBase + r) * (size_t)FIN + k0 + kc * 8);
      float4 v0 = ga[0], v1 = ga[1];
      us8 h, l;
      split8(v0, v1, h, l);
      int boff = r * 128 + ((kc * 16) ^ ((r & 7) << 4));
      *(us8*)(Abh + boff) = h;
      *(us8*)(Abl + boff) = l;
    }
    __syncthreads();
    // ---- compute: A from LDS, B direct from global (L2-resident W) ----
#pragma unroll
    for (int kk = 0; kk < 2; ++kk) {
      bf16x8 ah[4], al[4];
#pragma unroll
      for (int m = 0; m < 4; ++m) {
        int row  = wr * 64 + m * 16 + lr;
        int boff = row * 128 + ((kk * 64 + lg * 16) ^ ((row & 7) << 4));
        ah[m] = *(const bf16x8*)(Abh + boff);
        al[m] = *(const bf16x8*)(Abl + boff);
      }
#pragma unroll
      for (int n = 0; n < 2; ++n) {
        int col = colBase + wc * 32 + n * 16 + lr;
        size_t woff = (size_t)col * FIN + k0 + kk * 32 + lg * 8;
        bf16x8 bh = *(const bf16x8*)(Wh + woff);
        bf16x8 bl = *(const bf16x8*)(Wl + woff);
#pragma unroll
        for (int m = 0; m < 4; ++m) {
          acc[m][n] = __builtin_amdgcn_mfma_f32_16x16x32_bf16(ah[m], bh, acc[m][n], 0, 0, 0);
          acc[m][n] = __builtin_amdgcn_mfma_f32_16x16x32_bf16(ah[m], bl, acc[m][n], 0, 0, 0);
          acc[m][n] = __builtin_amdgcn_mfma_f32_16x16x32_bf16(al[m], bh, acc[m][n], 0, 0, 0);
        }
      }
    }
    __syncthreads();
  }

  if (MODE == 0) {
#pragma unroll
    for (int m = 0; m < 4; ++m) {
      size_t row = rowBase + wr * 64 + m * 16 + lg * 4;
#pragma unroll
      for (int n = 0; n < 2; ++n) {
        int col = colBase + wc * 32 + n * 16 + lr;
#pragma unroll
        for (int r = 0; r < 4; ++r)
          Y[(row + r) * (size_t)FOUT + col] = acc[m][n][r];
      }
    }
  }

  if (MODE <= 1) {
    // per-column partials over this block's 128 rows -> P[o][rblk]
    float ps1[2], ps2[2];
#pragma unroll
    for (int n = 0; n < 2; ++n) {
      ps1[n] = 0.f; ps2[n] = 0.f;
#pragma unroll
      for (int m = 0; m < 4; ++m)
#pragma unroll
        for (int r = 0; r < 4; ++r) {
          float v = acc[m][n][r];
          ps1[n] += v; ps2[n] += v * v;
        }
      ps1[n] += __shfl_xor(ps1[n], 16);
      ps1[n] += __shfl_xor(ps1[n], 32);
      ps2[n] += __shfl_xor(ps2[n], 16);
      ps2[n] += __shfl_xor(ps2[n], 32);
    }
    __syncthreads();
    float* red = (float*)lds;   // [2][4 waves][32 cols]
    if (lane < 16) {
#pragma unroll
      for (int n = 0; n < 2; ++n) {
        red[wid * 32 + n * 16 + lr]       = ps1[n];
        red[128 + wid * 32 + n * 16 + lr] = ps2[n];
      }
    }
    __syncthreads();
    if (tid < BN) {
      int c = tid, j = c & 31, wb = c >> 5;  // waves wb and wb+2 share col c
      float s1 = red[wb * 32 + j] + red[(wb + 2) * 32 + j];
      float s2 = red[128 + wb * 32 + j] + red[128 + (wb + 2) * 32 + j];
      P1[(size_t)(colBase + c) * NRBLK + rblk] = s1;
      P2[(size_t)(colBase + c) * NRBLK + rblk] = s2;
    }
  }

  if (MODE == 2) {
    const int b = rblk >> 6;   // 64 row-blocks per batch
#pragma unroll
    for (int n = 0; n < 2; ++n) {
      int col  = colBase + wc * 32 + n * 16 + lr;
      float sc = Sc[b * FOUT + col];
      float tc = Tc[b * FOUT + col];
#pragma unroll
      for (int m = 0; m < 4; ++m) {
        size_t row = rowBase + wr * 64 + m * 16 + lg * 4;
#pragma unroll
        for (int r = 0; r < 4; ++r)
          Y[(row + r) * (size_t)FOUT + col] = fmaf(acc[m][n][r], sc, tc);
      }
    }
  }
}

// One wave per (b,o) pair; coalesced 64-lane read over rblk, shuffle reduce.
__global__ void reduce_stats(const float* __restrict__ P1, const float* __restrict__ P2,
                             const float* __restrict__ gamma, const float* __restrict__ beta,
                             float* __restrict__ Sc, float* __restrict__ Tc) {
  int p = blockIdx.x * 4 + (threadIdx.x >> 6);   // 0..4095 = (b,o)
  int lane = threadIdx.x & 63;
  int b = p >> 8, o = p & 255;
  size_t base = (size_t)o * NRBLK + b * 64;
  float s1 = P1[base + lane];
  float s2 = P2[base + lane];
#pragma unroll
  for (int off = 32; off; off >>= 1) {
    s1 += __shfl_xor(s1, off);
    s2 += __shfl_xor(s2, off);
  }
  if (lane == 0) {
    float mean = s1 * (1.f / (float)NDIM);
    float var  = s2 * (1.f / (float)NDIM) - mean * mean;
    float g    = gamma[o] * rsqrtf(var + 1e-5f);
    Sc[p] = g;
    Tc[p] = beta[o] - mean * g;
  }
}

// Elementwise normalize of materialized y (Plan A).
__global__ void normalize_y(const float4* __restrict__ Yv,
                            const float* __restrict__ Sc, const float* __restrict__ Tc,
                            float4* __restrict__ Ov) {
  const int total = (BDIM * NDIM * FOUT) / 4;  // 8388608
  for (int i = blockIdx.x * blockDim.x + threadIdx.x; i < total;
       i += gridDim.x * blockDim.x) {
    float4 y = Yv[i];
    size_t e = (size_t)i * 4;
    int o = (int)(e & 255);
    int b = (int)(e >> 21);
    const float4 s = *(const float4*)(Sc + b * 256 + o);
    const float4 t = *(const float4*)(Tc + b * 256 + o);
    float4 r;
    r.x = fmaf(y.x, s.x, t.x);
    r.y = fmaf(y.y, s.y, t.y);
    r.z = fmaf(y.z, s.z, t.z);
    r.w = fmaf(y.w, s.w, t.w);
    Ov[i] = r;
  }
}

extern "C" void kernel_launch(void* const* d_in, const int* in_sizes, int n_in,
                              void* d_out, int out_size, void* d_ws, size_t ws_size,
                              hipStream_t stream) {
  const float* X     = (const float*)d_in[0];
  const float* W     = (const float*)d_in[1];
  // d_in[2] = bias: cancelled exactly by BN mean subtraction.
  const float* gamma = (const float*)d_in[3];
  const float* beta  = (const float*)d_in[4];
  float* out = (float*)d_out;
  float* wsf = (float*)d_ws;

  const size_t yElems = (size_t)BDIM * NDIM * FOUT;   // 33,554,432
  const size_t pElems = (size_t)FOUT * NRBLK;         // 262,144
  const size_t whFloats = (FOUT * FIN) / 2;           // 32,768 (ushort x 65536)
  const size_t needA = (yElems + 2 * pElems + 2 * 4096 + 2 * whFloats) * sizeof(float);

  dim3 grid(NRBLK, NCBLK), blk(NTHREADS);
  if (ws_size >= needA) {
    // Plan A: materialize y in ws, single GEMM pass.
    float* Y  = wsf;
    float* P1 = wsf + yElems;
    float* P2 = P1 + pElems;
    float* Sc = P2 + pElems;
    float* Tc = Sc + 4096;
    unsigned short* Wh = (unsigned short*)(Tc + 4096);
    unsigned short* Wl = Wh + FOUT * FIN;
    split_w<<<64, 256, 0, stream>>>((const float4*)W, (us4*)Wh, (us4*)Wl);
    fused_gemm<0><<<grid, blk, 0, stream>>>(X, Wh, Wl, Y, P1, P2, nullptr, nullptr);
    reduce_stats<<<1024, 256, 0, stream>>>(P1, P2, gamma, beta, Sc, Tc);
    normalize_y<<<4096, 256, 0, stream>>>((const float4*)Y, Sc, Tc, (float4*)out);
  } else {
    // Plan A': stats pass + recompute pass (tiny ws footprint).
    float* P1 = wsf;
    float* P2 = P1 + pElems;
    float* Sc = P2 + pElems;
    float* Tc = Sc + 4096;
    unsigned short* Wh = (unsigned short*)(Tc + 4096);
    unsigned short* Wl = Wh + FOUT * FIN;
    split_w<<<64, 256, 0, stream>>>((const float4*)W, (us4*)Wh, (us4*)Wl);
    fused_gemm<1><<<grid, blk, 0, stream>>>(X, Wh, Wl, nullptr, P1, P2, nullptr, nullptr);
    reduce_stats<<<1024, 256, 0, stream>>>(P1, P2, gamma, beta, Sc, Tc);
    fused_gemm<2><<<grid, blk, 0, stream>>>(X, Wh, Wl, out, P1, P2, Sc, Tc);
  }
}